// Round 8
// baseline (37516.531 us; speedup 1.0000x reference)
//
#include <hip/hip_runtime.h>

// TinyRNNPolicy: h_{t+1} = tanh(W h_t); action_t = tanh(mean(h_{t+1}[:2048]))
//
// R8: persistent kernel, 256 blocks x 512 threads (1 block/CU, 8 waves).
// W slice (128 floats/thread) AGPR-pinned (verified working in R6/R7:
// VGPR_Count=128 arch + 128 acc, FETCH dropped to ~0.6GB).
// Exchange: per-producer RECORDS. Block b publishes {16 h dwords | tag} in a
// 128B record: data stores -> s_waitcnt vmcnt(0) (ack) -> tag store (s+1).
// Consumers: 256 NARROW scouts, one tag dword each (R5-proven cheap poll
// shape -- R6/R7 showed wide polling causes ~100x fabric write amplification:
// 26-44 GB WRITE_SIZE). On tag match the scout reads the record's 16 floats
// and stages to LDS. This fuses barrier-detection with h-fetch (one less
// coherence hop than flag-barrier-then-reload) and drops the 256-wide AND.
// Ping-pong race-free: block Z produces tag s+2 into bufA only after reading
// all tags s+1, which were produced only after their blocks read ALL of
// bufA@s -> bufA@s is never overwritten before universal consumption.

#define N 4096
#define HALF 2048
#define BLOCKS 256
#define TPB 512
#define RPB 16        // rows per block
#define CCOLS 128     // cols per thread-chunk
#define NCH 32        // chunks (4096/128)
#define PAD 132       // LDS chunk stride in floats (132%32==4)
#define RECW 32       // record stride in dwords (128 B)

// ws layout (dword offsets); ws re-poisoned 0xAA each launch -> init kernel.
// Poison tag 0xAAAAAAAA never equals any real tag (0..n_steps+1).
#define WS_FLAGS 0            // 256 flags, stride 16 dwords (post-loop barrier)
#define WS_RECA  4096         // 256 records x 32 dwords (h ping)
#define WS_RECB  12288        // h pong
#define WS_ACC   20480        // accum[out_size] (fallback path only)
#define WS_PART  24576        // parts[n_steps*128] (big path)

typedef float f32x16 __attribute__((ext_vector_type(16)));

__device__ __forceinline__ float agent_ld(const float* p) {
    return __hip_atomic_load(p, __ATOMIC_RELAXED, __HIP_MEMORY_SCOPE_AGENT);
}
__device__ __forceinline__ void agent_st(float* p, float v) {
    __hip_atomic_store(p, v, __ATOMIC_RELAXED, __HIP_MEMORY_SCOPE_AGENT);
}
__device__ __forceinline__ unsigned agent_ldu(const unsigned* p) {
    return __hip_atomic_load(p, __ATOMIC_RELAXED, __HIP_MEMORY_SCOPE_AGENT);
}
__device__ __forceinline__ void agent_stu(unsigned* p, unsigned v) {
    __hip_atomic_store(p, v, __ATOMIC_RELAXED, __HIP_MEMORY_SCOPE_AGENT);
}

__device__ __forceinline__ float tanh_fast(float x) {
    x = fminf(fmaxf(x, -15.0f), 15.0f);   // clamp avoids inf/inf
    float e = __expf(2.0f * x);
    return (e - 1.0f) / (e + 1.0f);       // exact 0 at x==0
}

__global__ void rnn_init(const float* __restrict__ h0, float* __restrict__ ws, int n_out) {
    int i = blockIdx.x * blockDim.x + threadIdx.x;
    if (i < BLOCKS * 16) agent_stu((unsigned*)ws + WS_FLAGS + i, 0u);
    if (i < n_out) agent_st(ws + WS_ACC + i, 0.0f);
    if (i < N) {   // h_0 -> record data in buffer A
        float* recA = ws + WS_RECA;
        agent_st(recA + (i >> 4) * RECW + (i & 15), h0[i]);
    }
    if (i < BLOCKS) {  // tag 0 = h_0 ready in buffer A
        unsigned* recA = (unsigned*)ws + WS_RECA;
        agent_stu(recA + i * RECW + 16, 0u);
    }
}

__global__ void __launch_bounds__(TPB, 2)
rnn_persistent(const float* __restrict__ W, const int* __restrict__ pns,
               float* __restrict__ out, float* __restrict__ ws, int big) {
    const int b = blockIdx.x;
    const int t = threadIdx.x;
    const int lane = t & 63;
    const int wave = t >> 6;       // 0..7
    const int row = t & 15;        // row within block's 16 rows
    const int chunk = t >> 4;      // 0..31, 128-col chunk
    const int grow = b * RPB + row;

    // ---- one-time: W slice (128 floats/thread) -> AGPR-class vectors ----
    f32x16 wa[8];
    {
        const float4* Wv = (const float4*)(W + (size_t)grow * N + (size_t)chunk * CCOLS);
#pragma unroll
        for (int i = 0; i < 8; ++i) {
#pragma unroll
            for (int q = 0; q < 4; ++q) {
                float4 v = Wv[i * 4 + q];
                wa[i][4*q+0] = v.x; wa[i][4*q+1] = v.y;
                wa[i][4*q+2] = v.z; wa[i][4*q+3] = v.w;
            }
        }
    }

    const int n_steps = *pns;

    __shared__ float hs[NCH * PAD];   // padded h broadcast (~16.5 KiB)
    __shared__ float part[128];       // 8 waves x 16 rows

    unsigned* flags = (unsigned*)ws + WS_FLAGS;
    float* recA  = ws + WS_RECA;
    float* recB  = ws + WS_RECB;
    float* accum = ws + WS_ACC;
    float* parts = ws + WS_PART;

    for (int s = 0; s < n_steps; ++s) {
        // pin W into AGPRs each iteration (home class AGPR, no competitors)
#pragma unroll
        for (int i = 0; i < 8; ++i) asm volatile("" : "+a"(wa[i]));

        float* src = (s & 1) ? recB : recA;   // holds h_s (tag s)
        float* dst = (s & 1) ? recA : recB;   // will hold h_{s+1} (tag s+1)

        // ---- scouts: thread u<256 polls producer u's tag (1 dword), then
        //      reads its 16 h floats and stages to LDS (data IS the flag) ----
        if (t < BLOCKS) {
            const float* rec = src + t * RECW;
            const unsigned* tagp = (const unsigned*)rec + 16;
            unsigned spins = 0;
            while (agent_ldu(tagp) != (unsigned)s) {
                __builtin_amdgcn_s_sleep(1);
                if (++spins > (1u << 22)) break;   // fail loud, don't hang
            }
            float d[16];
#pragma unroll
            for (int j = 0; j < 16; ++j) d[j] = agent_ld(rec + j);
            // elements e = 16t..16t+15 -> chunk e>>7 = t>>3, offset 16*(t&7)+j
            float* dstl = &hs[(t >> 3) * PAD + 16 * (t & 7)];
#pragma unroll
            for (int j = 0; j < 16; j += 4)
                *(float4*)&dstl[j] = make_float4(d[j], d[j+1], d[j+2], d[j+3]);
        }
        __syncthreads();

        // ---- 128 FMAs over this thread's chunk; W sourced from AGPRs ----
        float s0 = 0.f, s1 = 0.f, s2 = 0.f, s3 = 0.f;
        const int hb = chunk * PAD;
#pragma unroll
        for (int k = 0; k < CCOLS; k += 4) {
            float4 hv = *(const float4*)&hs[hb + k];
            s0 = fmaf(wa[k >> 4][(k & 15) + 0], hv.x, s0);
            s1 = fmaf(wa[k >> 4][(k & 15) + 1], hv.y, s1);
            s2 = fmaf(wa[k >> 4][(k & 15) + 2], hv.z, s2);
            s3 = fmaf(wa[k >> 4][(k & 15) + 3], hv.w, s3);
        }
        float v = (s0 + s1) + (s2 + s3);

        // ---- intra-wave reduce: wave's 4 chunks -> lanes 0..15 (16 rows) ----
        v += __shfl_down(v, 32);
        v += __shfl_down(v, 16);
        if (lane < 16) part[wave * 16 + lane] = v;
        __syncthreads();

        // ---- wave 0: final reduce, tanh, publish record (data, ack, tag) ----
        if (wave == 0) {
            float hval = 0.0f;
            if (t < RPB) {
                float acc = 0.0f;
#pragma unroll
                for (int c = 0; c < TPB / 64; ++c) acc += part[c * 16 + t];
                hval = tanh_fast(acc);
                agent_st(dst + b * RECW + t, hval);   // 16 dwords, one line
            }
            // readout partial: sum of this block's 16 h values
            float r = (t < RPB) ? hval : 0.0f;
            r += __shfl_down(r, 8);
            r += __shfl_down(r, 4);
            r += __shfl_down(r, 2);
            r += __shfl_down(r, 1);
            if (t == 0 && b < (BLOCKS / 2)) {
                if (big) agent_st(parts + (size_t)s * 128 + b, r);
                else     atomicAdd(accum + s, r);
            }
            // order: data stores acked at coherence point, THEN tag store
            asm volatile("s_waitcnt vmcnt(0)" ::: "memory");
            if (t == 0)
                agent_stu((unsigned*)(dst + b * RECW) + 16, (unsigned)(s + 1));
        }

        // ---- fallback (!big): per-step flag barrier to finalize out[s] ----
        if (!big) {
            __syncthreads();
            if (wave == 0 && t == 0) agent_stu(flags + b * 16, (unsigned)(s + 1));
            if (t < BLOCKS) {
                unsigned spins = 0;
                while (agent_ldu(flags + t * 16) < (unsigned)(s + 1)) {
                    __builtin_amdgcn_s_sleep(1);
                    if (++spins > (1u << 22)) break;
                }
            }
            __syncthreads();
            if (b == 0 && t == 0)
                out[s] = tanh_fast(agent_ld(accum + s) * (1.0f / (float)HALF));
        }
        // big path: no per-step barrier; next step's scouts enforce order.
    }

    // ---- big path: one final barrier, then all outputs in parallel ----
    if (big) {
        __syncthreads();
        if (wave == 0) {
            asm volatile("s_waitcnt vmcnt(0)" ::: "memory");
            if (t == 0) agent_stu(flags + b * 16, (unsigned)(n_steps + 1));
        }
        if (t < BLOCKS) {
            unsigned spins = 0;
            while (agent_ldu(flags + t * 16) < (unsigned)(n_steps + 1)) {
                __builtin_amdgcn_s_sleep(1);
                if (++spins > (1u << 22)) break;
            }
        }
        __syncthreads();

        const int l = t & 63;
        for (int ss = b * 8 + (t >> 6); ss < n_steps; ss += BLOCKS * 8) {
            float v = agent_ld(parts + (size_t)ss * 128 + l)
                    + agent_ld(parts + (size_t)ss * 128 + 64 + l);
            v += __shfl_down(v, 32);
            v += __shfl_down(v, 16);
            v += __shfl_down(v, 8);
            v += __shfl_down(v, 4);
            v += __shfl_down(v, 2);
            v += __shfl_down(v, 1);
            if (l == 0) out[ss] = tanh_fast(v * (1.0f / (float)HALF));
        }
    }
}

extern "C" void kernel_launch(void* const* d_in, const int* in_sizes, int n_in,
                              void* d_out, int out_size, void* d_ws, size_t ws_size,
                              hipStream_t stream) {
    const float* W  = (const float*)d_in[0];
    const float* h0 = (const float*)d_in[1];
    const int*  pns = (const int*)d_in[2];
    float* out = (float*)d_out;
    float* ws  = (float*)d_ws;

    size_t need = ((size_t)WS_PART + (size_t)out_size * 128) * 4;
    int big = (ws_size >= need) ? 1 : 0;

    int n_init = out_size > N ? out_size : N;
    rnn_init<<<(n_init + 255) / 256, 256, 0, stream>>>(h0, ws, out_size);
    rnn_persistent<<<BLOCKS, TPB, 0, stream>>>(W, pns, out, ws, big);
}